// Round 2
// 593.911 us; speedup vs baseline: 1.1290x; 1.1290x over previous
//
#include <hip/hip_runtime.h>

// Problem constants (B,T,C,H,E = 8,2048,1024,16,64; TOP_K=38)
#define T_LEN 2048
#define B_DIM 8
#define C_DIM 1024
#define TOPK  38

typedef _Float16 half8 __attribute__((ext_vector_type(8)));
typedef float  floatx4 __attribute__((ext_vector_type(4)));
typedef unsigned int u32;

__device__ __forceinline__ void async16(const void* g, void* l) {
  __builtin_amdgcn_global_load_lds(
      (const __attribute__((address_space(1))) u32*)g,
      (__attribute__((address_space(3))) u32*)l, 16, 0, 0);
}

// ---------------------------------------------------------------- zero fill
__global__ __launch_bounds__(256) void zero_kernel(float* __restrict__ p, int n) {
  int i = blockIdx.x * 256 + threadIdx.x;
  if (i < n) p[i] = 0.0f;
}

// ---------------------------------------------------------------- f32 -> fp16 (8/thread)
__global__ __launch_bounds__(256) void cvt_f16_kernel(
    const float* __restrict__ src, _Float16* __restrict__ dst, int n8) {
  int i = blockIdx.x * 256 + threadIdx.x;
  if (i >= n8) return;
  floatx4 a = ((const floatx4*)src)[i * 2];
  floatx4 b = ((const floatx4*)src)[i * 2 + 1];
  half8 o;
  #pragma unroll
  for (int j = 0; j < 4; ++j) { o[j] = (_Float16)a[j]; o[j + 4] = (_Float16)b[j]; }
  ((half8*)dst)[i] = o;
}

// ---------------------------------------------------------------- W [K,N] f32 -> Wt [N,K] fp16 (batched x3)
__global__ __launch_bounds__(256) void wt3_kernel(
    const float* __restrict__ w0, const float* __restrict__ w1,
    const float* __restrict__ w2, _Float16* __restrict__ d0,
    _Float16* __restrict__ d1, _Float16* __restrict__ d2) {
  const float* src = blockIdx.z == 0 ? w0 : (blockIdx.z == 1 ? w1 : w2);
  _Float16*    dst = blockIdx.z == 0 ? d0 : (blockIdx.z == 1 ? d1 : d2);
  __shared__ _Float16 tile[64][65];
  int k0 = blockIdx.y * 64, n0 = blockIdx.x * 64;
  int tx = threadIdx.x & 63, ty = threadIdx.x >> 6;  // ty 0..3
  #pragma unroll
  for (int j = 0; j < 16; ++j) {
    int r = j * 4 + ty;
    tile[r][tx] = (_Float16)src[(size_t)(k0 + r) * C_DIM + n0 + tx];
  }
  __syncthreads();
  #pragma unroll
  for (int j = 0; j < 16; ++j) {
    int r = j * 4 + ty;
    dst[(size_t)(n0 + r) * C_DIM + k0 + tx] = tile[tx][r];
  }
}

// ---------------------------------------------------------------- fp16 NT GEMM (m97-style)
// C[m,n] = sum_k A[m*K+k]*B[n*K+k]; both operands fp16, K-contiguous.
// EPI: 0 = fp16 store + bias, 1 = f32 store + bias, 2 = Gram diagonal reduce
template <int EPI>
__global__ __launch_bounds__(256, 3) void gemm_f16_kernel(
    const _Float16* __restrict__ A, const _Float16* __restrict__ B,
    const float* __restrict__ bias, void* __restrict__ outv,
    float* __restrict__ meanv, int N, int K,
    long long aStride, long long bStride) {
  __shared__ __align__(16) _Float16 lA[128 * 64];
  __shared__ __align__(16) _Float16 lB[128 * 64];

  const int tid = threadIdx.x;
  const int bm = blockIdx.x, bn = blockIdx.y, bz = blockIdx.z;
  const int lane = tid & 63, w = tid >> 6;
  const int wm = w >> 1, wn = w & 1;     // 2x2 waves -> 64x64 tiles
  const int lr = lane & 15, lg = lane >> 4;

  const _Float16* Ab = A + (long long)bz * aStride;
  const _Float16* Bb = B + (long long)bz * bStride;

  const int lrow = lane >> 3;            // 0..7
  const int lcol = (lane & 7) * 8;       // element col within 64

  const _Float16* pA[4];
  const _Float16* pB[4];
  _Float16* dA[4];
  _Float16* dB[4];
  #pragma unroll
  for (int j = 0; j < 4; ++j) {
    int r = w * 32 + j * 8;              // wave-uniform row base of this 8-row slab
    pA[j] = Ab + (long long)(bm * 128 + r + lrow) * K + lcol;
    pB[j] = Bb + (long long)(bn * 128 + r + lrow) * K + lcol;
    dA[j] = &lA[r * 64];                 // wave-uniform LDS dest (lane x 16B appended by HW)
    dB[j] = &lB[r * 64];
  }

  floatx4 acc[4][4];
  #pragma unroll
  for (int i = 0; i < 4; ++i)
    #pragma unroll
    for (int j = 0; j < 4; ++j) { acc[i][j][0]=0.f; acc[i][j][1]=0.f; acc[i][j][2]=0.f; acc[i][j][3]=0.f; }

  const int nk = K >> 6;
  for (int kt = 0; kt < nk; ++kt) {
    __syncthreads();                     // protect LDS vs previous iteration's reads
    #pragma unroll
    for (int j = 0; j < 4; ++j) {
      async16(pA[j], dA[j]);
      async16(pB[j], dB[j]);
      pA[j] += 64; pB[j] += 64;
    }
    __syncthreads();                     // compiler drains vmcnt before s_barrier
    #pragma unroll
    for (int s = 0; s < 2; ++s) {
      half8 af[4], bf[4];
      #pragma unroll
      for (int mi = 0; mi < 4; ++mi)
        af[mi] = *(const half8*)&lA[(wm * 64 + mi * 16 + lr) * 64 + s * 32 + lg * 8];
      #pragma unroll
      for (int ni = 0; ni < 4; ++ni)
        bf[ni] = *(const half8*)&lB[(wn * 64 + ni * 16 + lr) * 64 + s * 32 + lg * 8];
      #pragma unroll
      for (int mi = 0; mi < 4; ++mi)
        #pragma unroll
        for (int ni = 0; ni < 4; ++ni)
          acc[mi][ni] = __builtin_amdgcn_mfma_f32_16x16x32_f16(
              af[mi], bf[ni], acc[mi][ni], 0, 0, 0);
    }
  }

  if constexpr (EPI == 2) {
    // Diagonal reduce: G[m][n] contributes to l = (m-n) mod T.
    // d = (wm-wn)*64 + (mi-ni)*16 + (lg*4 + i) - lr.
    // Step 1: register pre-reduction 64 -> 28 values (depends on mi-ni and i only).
    float s[7][4];
    #pragma unroll
    for (int dd = 0; dd < 7; ++dd)
      #pragma unroll
      for (int i = 0; i < 4; ++i) s[dd][i] = 0.0f;
    #pragma unroll
    for (int mi = 0; mi < 4; ++mi)
      #pragma unroll
      for (int ni = 0; ni < 4; ++ni)
        #pragma unroll
        for (int i = 0; i < 4; ++i)
          s[mi - ni + 3][i] += acc[mi][ni][i];

    // Step 2: contention-free binning via per-(wave, lg-group) private arrays,
    // stride 144 floats (144 % 32 == 16 -> lg arrays alias banks at most 2-way = free).
    // MUST be atomicAdd: plain "+=" lets the compiler batch the 28 ds_reads ahead of
    // the writes (distinct constant offsets from one base), and addresses DO collide
    // cross-lane across unroll steps (lane lr at (dd,i) vs lane lr+1 at (dd,i+1)) ->
    // lost updates (round-1 fail, absmax 1.43). Atomics make each RMW indivisible;
    // within one atomic instruction all 64 lanes hit distinct addresses -> no
    // same-address serialization (the original diag4 layout had 4-way).
    __shared__ float bins[4 * 4 * 144];              // 9216 B
    float* wb = &bins[w * 576];
    for (int i = lane; i < 576; i += 64) wb[i] = 0.0f;   // own-wave zero; atomics below are ordered after
    float* myArr = wb + lg * 144;
    const int jbase = 15 - lr;
    #pragma unroll
    for (int dd = 0; dd < 7; ++dd)
      #pragma unroll
      for (int i = 0; i < 4; ++i)
        atomicAdd(&myArr[jbase + dd * 16 + i], s[dd][i]);
    __syncthreads();

    // Step 3: merge 16 arrays + one global atomic per diagonal.
    // bin t (0..254) = (wm-wn)*64 + 64 + 4*lg + j, j in [0,114].
    if (tid < 255) {
      float tot = 0.0f;
      #pragma unroll
      for (int ww = 0; ww < 4; ++ww) {
        const int dw = (ww >> 1) - (ww & 1);          // wm - wn
        const int off = 64 + 64 * dw;                 // {64, 0, 128, 64}
        #pragma unroll
        for (int g2 = 0; g2 < 4; ++g2) {
          int j = tid - off - 4 * g2;
          if (j >= 0 && j <= 114) tot += bins[ww * 576 + g2 * 144 + j];
        }
      }
      int l = (bm * 128 - bn * 128 - 127 + tid) & (T_LEN - 1);  // mod 2048
      atomicAdd(&meanv[bz * T_LEN + l], tot);
    }
  } else {
    float bvs[4];
    #pragma unroll
    for (int ni = 0; ni < 4; ++ni) {
      int gc = bn * 128 + wn * 64 + ni * 16 + lr;
      bvs[ni] = bias ? bias[gc & (C_DIM - 1)] : 0.0f;
    }
    #pragma unroll
    for (int mi = 0; mi < 4; ++mi)
      #pragma unroll
      for (int ni = 0; ni < 4; ++ni) {
        int gc = bn * 128 + wn * 64 + ni * 16 + lr;
        #pragma unroll
        for (int i = 0; i < 4; ++i) {
          int gr = bm * 128 + wm * 64 + mi * 16 + lg * 4 + i;
          float v = acc[mi][ni][i] + bvs[ni];
          long long idx = (long long)gr * N + gc;
          if constexpr (EPI == 1) ((float*)outv)[idx] = v;
          else                    ((_Float16*)outv)[idx] = (_Float16)v;
        }
      }
  }
}

// ---------------------------------------------------------------- top-k + softmax
__global__ __launch_bounds__(256) void topk_softmax_kernel(
    const float* __restrict__ meanv, float* __restrict__ wgt, int* __restrict__ dly) {
  __shared__ float vals[T_LEN];
  __shared__ float swv[4];
  __shared__ int   swi[4];
  __shared__ float selw[TOPK];
  __shared__ int   seli[TOPK];
  int b = blockIdx.x, tid = threadIdx.x;
  for (int i = tid; i < T_LEN; i += 256) vals[i] = meanv[b * T_LEN + i] * (1.0f / 1024.0f);
  __syncthreads();
  for (int it = 0; it < TOPK; ++it) {
    float bv = -3.4e38f; int bi = T_LEN - 1;
    for (int i = tid; i < T_LEN; i += 256) {
      float v = vals[i];
      if (v > bv || (v == bv && i < bi)) { bv = v; bi = i; }
    }
    #pragma unroll
    for (int off = 32; off > 0; off >>= 1) {
      float ov = __shfl_down(bv, off);
      int   oi = __shfl_down(bi, off);
      if (ov > bv || (ov == bv && oi < bi)) { bv = ov; bi = oi; }
    }
    if ((tid & 63) == 0) { swv[tid >> 6] = bv; swi[tid >> 6] = bi; }
    __syncthreads();
    if (tid == 0) {
      #pragma unroll
      for (int ww = 1; ww < 4; ++ww) {
        float ov = swv[ww]; int oi = swi[ww];
        if (ov > bv || (ov == bv && oi < bi)) { bv = ov; bi = oi; }
      }
      if (bi < 0) bi = 0; if (bi > T_LEN - 1) bi = T_LEN - 1;
      selw[it] = bv; seli[it] = bi;
      vals[bi] = -3.4e38f;
    }
    __syncthreads();
  }
  if (tid == 0) {
    float m = selw[0], s = 0.0f, e[TOPK];
    for (int i = 0; i < TOPK; ++i) { e[i] = expf(selw[i] - m); s += e[i]; }
    float inv = 1.0f / s;
    for (int i = 0; i < TOPK; ++i) { wgt[b * TOPK + i] = e[i] * inv; dly[b * TOPK + i] = seli[i]; }
  }
}

// ---------------------------------------------------------------- aggregation (+reference's reshape)
// V2[b, t'=h*128+l/16, c'=(l%16)*64+e] = sum_k w[b,k] * V[b, (l+d_k)%T, h*64+e]
// Batch pinned to XCD: b = blockIdx.x % 8 (dispatch round-robins blocks over 8 XCDs),
// so each batch's 4 MiB V slab stays resident in exactly one XCD's 4 MiB L2.
// V2 stores are nontemporal so the streaming writes don't evict V.
__global__ __launch_bounds__(256) void aggregate_kernel(
    const _Float16* __restrict__ V, const float* __restrict__ wgt,
    const int* __restrict__ dly, _Float16* __restrict__ V2) {
  int b = blockIdx.x & 7;
  int g = (blockIdx.x >> 3) * 256 + threadIdx.x;  // 0 .. T*C/8-1
  int c8 = g & 127;
  int tp = g >> 7;                              // output row t'
  int h = tp >> 7, lhi = tp & 127;
  int cp = c8 << 3;
  int e0 = cp & 63, lo = cp >> 6;
  int l = lhi * 16 + lo;
  int ch = h * 64 + e0;
  float acc[8];
  #pragma unroll
  for (int j = 0; j < 8; ++j) acc[j] = 0.0f;
  const long long vbase = (long long)b * T_LEN * C_DIM;
  for (int k = 0; k < TOPK; ++k) {
    float w = wgt[b * TOPK + k];
    int d = dly[b * TOPK + k];
    int ts = (l + d) & (T_LEN - 1);
    half8 vv = *(const half8*)(V + vbase + (long long)ts * C_DIM + ch);
    #pragma unroll
    for (int j = 0; j < 8; ++j) acc[j] += w * (float)vv[j];
  }
  half8 o;
  #pragma unroll
  for (int j = 0; j < 8; ++j) o[j] = (_Float16)acc[j];
  __builtin_nontemporal_store(o, (half8*)(V2 + vbase + (long long)tp * C_DIM + cp));
}

// ---------------------------------------------------------------- launcher
extern "C" void kernel_launch(void* const* d_in, const int* in_sizes, int n_in,
                              void* d_out, int out_size, void* d_ws, size_t ws_size,
                              hipStream_t stream) {
  const float* x  = (const float*)d_in[0];
  const float* Wq = (const float*)d_in[1];
  const float* bq = (const float*)d_in[2];
  const float* Wk = (const float*)d_in[3];
  const float* bk = (const float*)d_in[4];
  const float* Wv = (const float*)d_in[5];
  const float* bv = (const float*)d_in[6];
  const float* Wp = (const float*)d_in[7];
  const float* bp = (const float*)d_in[8];
  (void)bq; (void)bk;  // constant (l-independent) shift of meanv; top-k order and
                       // softmax are shift-invariant (and both are zeros here anyway)

  // Q.K^T == X (Wq Wk^T) X^T  -> drop the K projection entirely.
  // d_out (64 MiB f32 out) doubles as scratch:
  //   [0, 32MiB)   xh fp16 (x converted)  -- live until V-proj done
  //   [32,34) Wqh  [34,36) Wkh  (row-major fp16)   [36,38) Wvt   [38,40) Mt2
  // ws (>= 64MiB + 72KiB, proven):
  //   [0, 32MiB)   XMh fp16 -> later V2 fp16
  //   [32, 64MiB)  V fp16   -> later Wpt
  //   tail: meanv (64KiB), wgt, dly
  const size_t SZ_H = (size_t)B_DIM * T_LEN * C_DIM * 2;   // 32 MiB
  const size_t NEEDED = 2 * SZ_H + 65536 + 8192;
  if (ws_size < NEEDED) return;

  char* ws = (char*)d_ws;
  _Float16* XMh = (_Float16*)ws;
  _Float16* V   = (_Float16*)(ws + SZ_H);
  float* meanv = (float*)(ws + 2 * SZ_H);
  float* wgt   = (float*)(ws + 2 * SZ_H + 65536);
  int*   dly   = (int*)(ws + 2 * SZ_H + 65536 + 4096);
  _Float16* V2  = (_Float16*)ws;             // after Gram (XMh dead)
  _Float16* Wpt = (_Float16*)(ws + SZ_H);    // after agg (V dead), 2 MiB

  char* dob = (char*)d_out;
  _Float16* xh  = (_Float16*)dob;
  _Float16* Wqh = (_Float16*)(dob + 32 * 1048576);
  _Float16* Wkh = (_Float16*)(dob + 34 * 1048576);
  _Float16* Wvt = (_Float16*)(dob + 36 * 1048576);
  _Float16* Mt2 = (_Float16*)(dob + 38 * 1048576);

  const int M = B_DIM * T_LEN;  // 16384
  const long long TC = (long long)T_LEN * C_DIM;

  zero_kernel<<<(B_DIM * T_LEN) / 256, 256, 0, stream>>>(meanv, B_DIM * T_LEN);
  cvt_f16_kernel<<<(M * C_DIM / 8) / 256, 256, 0, stream>>>(x, xh, M * C_DIM / 8);
  cvt_f16_kernel<<<(C_DIM * C_DIM / 8) / 256, 256, 0, stream>>>(Wq, Wqh, C_DIM * C_DIM / 8);
  cvt_f16_kernel<<<(C_DIM * C_DIM / 8) / 256, 256, 0, stream>>>(Wk, Wkh, C_DIM * C_DIM / 8);

  dim3 tgrid(16, 16, 1);
  wt3_kernel<<<tgrid, 256, 0, stream>>>(Wv, Wv, Wv, Wvt, Wvt, Wvt);   // z=0 slice only

  dim3 pgrid(M / 128, C_DIM / 128, 1);        // (128, 8)
  dim3 mgrid(C_DIM / 128, C_DIM / 128, 1);    // (8, 8)
  dim3 ggrid(T_LEN / 128, T_LEN / 128, B_DIM);// (16, 16, 8)

  // Mt2[b,a] = sum_o Wk[b,o] * Wq[a,o]   (both row-major, K-contiguous: NT gemm)
  gemm_f16_kernel<0><<<mgrid, 256, 0, stream>>>(Wkh, Wqh, nullptr, Mt2, nullptr, C_DIM, C_DIM, 0, 0);
  // XM[t,b] = sum_a x[t,a] * Mt2[b,a] = sum_o Q[t,o] Wk[b,o]
  gemm_f16_kernel<0><<<pgrid, 256, 0, stream>>>(xh, Mt2, nullptr, XMh, nullptr, C_DIM, C_DIM, 0, 0);
  // G[t,u] = sum_b XM[t,b] x[u,b] = sum_o Q[t,o] K[u,o]  -> diagonal reduce
  gemm_f16_kernel<2><<<ggrid, 256, 0, stream>>>(XMh, xh, nullptr, nullptr, meanv, T_LEN, C_DIM, TC, TC);

  topk_softmax_kernel<<<B_DIM, 256, 0, stream>>>(meanv, wgt, dly);

  // V = xh @ Wvt + bv  (XMh dead after Gram; stream-ordered)
  gemm_f16_kernel<0><<<pgrid, 256, 0, stream>>>(xh, Wvt, bv, V, nullptr, C_DIM, C_DIM, 0, 0);

  aggregate_kernel<<<(T_LEN * C_DIM / 8 / 256) * B_DIM, 256, 0, stream>>>(V, wgt, dly, V2);

  wt3_kernel<<<tgrid, 256, 0, stream>>>(Wp, Wp, Wp, Wpt, Wpt, Wpt);  // z=0 slice only

  // out = V2 @ Wpt + bp -> d_out f32 (xh + weight slots dead)
  gemm_f16_kernel<1><<<pgrid, 256, 0, stream>>>(V2, Wpt, bp, d_out, nullptr, C_DIM, C_DIM, 0, 0);
}

// Round 3
// 552.210 us; speedup vs baseline: 1.2142x; 1.0755x over previous
//
#include <hip/hip_runtime.h>

// Problem constants (B,T,C,H,E = 8,2048,1024,16,64; TOP_K=38)
#define T_LEN 2048
#define B_DIM 8
#define C_DIM 1024
#define TOPK  38

typedef _Float16 half8 __attribute__((ext_vector_type(8)));
typedef float  floatx4 __attribute__((ext_vector_type(4)));
typedef unsigned int u32;

__device__ __forceinline__ void async16(const void* g, void* l) {
  __builtin_amdgcn_global_load_lds(
      (const __attribute__((address_space(1))) u32*)g,
      (__attribute__((address_space(3))) u32*)l, 16, 0, 0);
}

// ---------------------------------------------------------------- zero fill
__global__ __launch_bounds__(256) void zero_kernel(float* __restrict__ p, int n) {
  int i = blockIdx.x * 256 + threadIdx.x;
  if (i < n) p[i] = 0.0f;
}

// ---------------------------------------------------------------- f32 -> fp16 (8/thread)
__global__ __launch_bounds__(256) void cvt_f16_kernel(
    const float* __restrict__ src, _Float16* __restrict__ dst, int n8) {
  int i = blockIdx.x * 256 + threadIdx.x;
  if (i >= n8) return;
  floatx4 a = ((const floatx4*)src)[i * 2];
  floatx4 b = ((const floatx4*)src)[i * 2 + 1];
  half8 o;
  #pragma unroll
  for (int j = 0; j < 4; ++j) { o[j] = (_Float16)a[j]; o[j + 4] = (_Float16)b[j]; }
  ((half8*)dst)[i] = o;
}

// ---------------------------------------------------------------- W [K,N] f32 -> Wt [N,K] fp16 (batched x3)
__global__ __launch_bounds__(256) void wt3_kernel(
    const float* __restrict__ w0, const float* __restrict__ w1,
    const float* __restrict__ w2, _Float16* __restrict__ d0,
    _Float16* __restrict__ d1, _Float16* __restrict__ d2) {
  const float* src = blockIdx.z == 0 ? w0 : (blockIdx.z == 1 ? w1 : w2);
  _Float16*    dst = blockIdx.z == 0 ? d0 : (blockIdx.z == 1 ? d1 : d2);
  __shared__ _Float16 tile[64][65];
  int k0 = blockIdx.y * 64, n0 = blockIdx.x * 64;
  int tx = threadIdx.x & 63, ty = threadIdx.x >> 6;  // ty 0..3
  #pragma unroll
  for (int j = 0; j < 16; ++j) {
    int r = j * 4 + ty;
    tile[r][tx] = (_Float16)src[(size_t)(k0 + r) * C_DIM + n0 + tx];
  }
  __syncthreads();
  #pragma unroll
  for (int j = 0; j < 16; ++j) {
    int r = j * 4 + ty;
    dst[(size_t)(n0 + r) * C_DIM + k0 + tx] = tile[tx][r];
  }
}

// ---------------------------------------------------------------- fp16 NT GEMM (m97-style + read swizzle)
// C[m,n] = sum_k A[m*K+k]*B[n*K+k]; both operands fp16, K-contiguous.
// EPI: 0 = fp16 store + bias, 1 = f32 store + bias, 2 = Gram diagonal reduce
//
// LDS tiles are 128 rows x 64 fp16 (128 B/row). Unswizzled, the fragment read
// puts 16 lanes (lr=0..15) on 16 different rows at the SAME 16-B chunk ->
// same 4 banks -> 16-way conflict (measured 2.5e7 conflict-cycles/dispatch).
// Fix (rule 21: both-sides-or-neither with global_load_lds): keep the LDS dest
// linear, permute the GLOBAL source column chunk by the involution
//   chunk' = chunk ^ (row & 7)        (chunk = 16-B column index, 0..7)
// and read fragments at the same XOR'd chunk. After the swizzle each 16-lane
// quarter-wave covers 8 distinct chunks x 2 rows = 2-way (free, m136).
// Pure placement permutation -> bit-identical arithmetic.
template <int EPI>
__global__ __launch_bounds__(256, 3) void gemm_f16_kernel(
    const _Float16* __restrict__ A, const _Float16* __restrict__ B,
    const float* __restrict__ bias, void* __restrict__ outv,
    float* __restrict__ meanv, int N, int K,
    long long aStride, long long bStride) {
  __shared__ __align__(16) _Float16 lA[128 * 64];
  __shared__ __align__(16) _Float16 lB[128 * 64];

  const int tid = threadIdx.x;
  const int bm = blockIdx.x, bn = blockIdx.y, bz = blockIdx.z;
  const int lane = tid & 63, w = tid >> 6;
  const int wm = w >> 1, wn = w & 1;     // 2x2 waves -> 64x64 tiles
  const int lr = lane & 15, lg = lane >> 4;

  const _Float16* Ab = A + (long long)bz * aStride;
  const _Float16* Bb = B + (long long)bz * bStride;

  const int lrow = lane >> 3;            // 0..7 = row within 8-row slab (= row&7)
  // swizzled source chunk: (lane&7) ^ (row&7), in elements (x8)
  const int lcol = (((lane & 7) ^ lrow) * 8);

  const _Float16* pA[4];
  const _Float16* pB[4];
  _Float16* dA[4];
  _Float16* dB[4];
  #pragma unroll
  for (int j = 0; j < 4; ++j) {
    int r = w * 32 + j * 8;              // wave-uniform row base (multiple of 8)
    pA[j] = Ab + (long long)(bm * 128 + r + lrow) * K + lcol;
    pB[j] = Bb + (long long)(bn * 128 + r + lrow) * K + lcol;
    dA[j] = &lA[r * 64];                 // linear LDS dest (lane x 16B appended by HW)
    dB[j] = &lB[r * 64];
  }

  // fragment-read chunk offset: logical chunk (s*4 + lg), stored at chunk ^ (lr&7).
  // bitwise: elem_off = ((s ^ ((lr>>2)&1))*32) | ((lg ^ (lr&3))*8) = coff ^ (s*32)
  const int coff = (((lr >> 2) & 1) * 32) | ((lg ^ (lr & 3)) * 8);

  floatx4 acc[4][4];
  #pragma unroll
  for (int i = 0; i < 4; ++i)
    #pragma unroll
    for (int j = 0; j < 4; ++j) { acc[i][j][0]=0.f; acc[i][j][1]=0.f; acc[i][j][2]=0.f; acc[i][j][3]=0.f; }

  const int nk = K >> 6;
  for (int kt = 0; kt < nk; ++kt) {
    __syncthreads();                     // protect LDS vs previous iteration's reads
    #pragma unroll
    for (int j = 0; j < 4; ++j) {
      async16(pA[j], dA[j]);
      async16(pB[j], dB[j]);
      pA[j] += 64; pB[j] += 64;
    }
    __syncthreads();                     // compiler drains vmcnt before s_barrier
    #pragma unroll
    for (int s = 0; s < 2; ++s) {
      const int so = coff ^ (s * 32);
      half8 af[4], bf[4];
      #pragma unroll
      for (int mi = 0; mi < 4; ++mi)
        af[mi] = *(const half8*)&lA[(wm * 64 + mi * 16 + lr) * 64 + so];
      #pragma unroll
      for (int ni = 0; ni < 4; ++ni)
        bf[ni] = *(const half8*)&lB[(wn * 64 + ni * 16 + lr) * 64 + so];
      #pragma unroll
      for (int mi = 0; mi < 4; ++mi)
        #pragma unroll
        for (int ni = 0; ni < 4; ++ni)
          acc[mi][ni] = __builtin_amdgcn_mfma_f32_16x16x32_f16(
              af[mi], bf[ni], acc[mi][ni], 0, 0, 0);
    }
  }

  if constexpr (EPI == 2) {
    // Diagonal reduce: G[m][n] contributes to l = (m-n) mod T.
    // d = (wm-wn)*64 + (mi-ni)*16 + (lg*4 + i) - lr.
    // Step 1: register pre-reduction 64 -> 28 values (depends on mi-ni and i only).
    float s[7][4];
    #pragma unroll
    for (int dd = 0; dd < 7; ++dd)
      #pragma unroll
      for (int i = 0; i < 4; ++i) s[dd][i] = 0.0f;
    #pragma unroll
    for (int mi = 0; mi < 4; ++mi)
      #pragma unroll
      for (int ni = 0; ni < 4; ++ni)
        #pragma unroll
        for (int i = 0; i < 4; ++i)
          s[mi - ni + 3][i] += acc[mi][ni][i];

    // Step 2: contention-free binning via per-(wave, lg-group) private arrays,
    // stride 144 floats (144 % 32 == 16 -> lg arrays alias banks at most 2-way = free).
    // MUST be atomicAdd: plain "+=" lets the compiler batch the 28 ds_reads ahead of
    // the writes and addresses collide cross-lane across unroll steps -> lost
    // updates (round-1 fail). Atomics make each RMW indivisible; within one atomic
    // instruction all 64 lanes hit distinct addresses -> no same-address serialization.
    __shared__ float bins[4 * 4 * 144];              // 9216 B
    float* wb = &bins[w * 576];
    for (int i = lane; i < 576; i += 64) wb[i] = 0.0f;   // own-wave zero; atomics ordered after
    float* myArr = wb + lg * 144;
    const int jbase = 15 - lr;
    #pragma unroll
    for (int dd = 0; dd < 7; ++dd)
      #pragma unroll
      for (int i = 0; i < 4; ++i)
        atomicAdd(&myArr[jbase + dd * 16 + i], s[dd][i]);
    __syncthreads();

    // Step 3: merge 16 arrays + one global atomic per diagonal.
    // bin t (0..254) = (wm-wn)*64 + 64 + 4*lg + j, j in [0,114].
    if (tid < 255) {
      float tot = 0.0f;
      #pragma unroll
      for (int ww = 0; ww < 4; ++ww) {
        const int dw = (ww >> 1) - (ww & 1);          // wm - wn
        const int off = 64 + 64 * dw;                 // {64, 0, 128, 64}
        #pragma unroll
        for (int g2 = 0; g2 < 4; ++g2) {
          int j = tid - off - 4 * g2;
          if (j >= 0 && j <= 114) tot += bins[ww * 576 + g2 * 144 + j];
        }
      }
      int l = (bm * 128 - bn * 128 - 127 + tid) & (T_LEN - 1);  // mod 2048
      atomicAdd(&meanv[bz * T_LEN + l], tot);
    }
  } else {
    float bvs[4];
    #pragma unroll
    for (int ni = 0; ni < 4; ++ni) {
      int gc = bn * 128 + wn * 64 + ni * 16 + lr;
      bvs[ni] = bias ? bias[gc & (C_DIM - 1)] : 0.0f;
    }
    #pragma unroll
    for (int mi = 0; mi < 4; ++mi)
      #pragma unroll
      for (int ni = 0; ni < 4; ++ni) {
        int gc = bn * 128 + wn * 64 + ni * 16 + lr;
        #pragma unroll
        for (int i = 0; i < 4; ++i) {
          int gr = bm * 128 + wm * 64 + mi * 16 + lg * 4 + i;
          float v = acc[mi][ni][i] + bvs[ni];
          long long idx = (long long)gr * N + gc;
          if constexpr (EPI == 1) ((float*)outv)[idx] = v;
          else                    ((_Float16*)outv)[idx] = (_Float16)v;
        }
      }
  }
}

// ---------------------------------------------------------------- top-k + softmax
__global__ __launch_bounds__(256) void topk_softmax_kernel(
    const float* __restrict__ meanv, float* __restrict__ wgt, int* __restrict__ dly) {
  __shared__ float vals[T_LEN];
  __shared__ float swv[4];
  __shared__ int   swi[4];
  __shared__ float selw[TOPK];
  __shared__ int   seli[TOPK];
  int b = blockIdx.x, tid = threadIdx.x;
  for (int i = tid; i < T_LEN; i += 256) vals[i] = meanv[b * T_LEN + i] * (1.0f / 1024.0f);
  __syncthreads();
  for (int it = 0; it < TOPK; ++it) {
    float bv = -3.4e38f; int bi = T_LEN - 1;
    for (int i = tid; i < T_LEN; i += 256) {
      float v = vals[i];
      if (v > bv || (v == bv && i < bi)) { bv = v; bi = i; }
    }
    #pragma unroll
    for (int off = 32; off > 0; off >>= 1) {
      float ov = __shfl_down(bv, off);
      int   oi = __shfl_down(bi, off);
      if (ov > bv || (ov == bv && oi < bi)) { bv = ov; bi = oi; }
    }
    if ((tid & 63) == 0) { swv[tid >> 6] = bv; swi[tid >> 6] = bi; }
    __syncthreads();
    if (tid == 0) {
      #pragma unroll
      for (int ww = 1; ww < 4; ++ww) {
        float ov = swv[ww]; int oi = swi[ww];
        if (ov > bv || (ov == bv && oi < bi)) { bv = ov; bi = oi; }
      }
      if (bi < 0) bi = 0; if (bi > T_LEN - 1) bi = T_LEN - 1;
      selw[it] = bv; seli[it] = bi;
      vals[bi] = -3.4e38f;
    }
    __syncthreads();
  }
  if (tid == 0) {
    float m = selw[0], s = 0.0f, e[TOPK];
    for (int i = 0; i < TOPK; ++i) { e[i] = expf(selw[i] - m); s += e[i]; }
    float inv = 1.0f / s;
    for (int i = 0; i < TOPK; ++i) { wgt[b * TOPK + i] = e[i] * inv; dly[b * TOPK + i] = seli[i]; }
  }
}

// ---------------------------------------------------------------- aggregation (+reference's reshape)
// V2[b, t'=h*128+l/16, c'=(l%16)*64+e] = sum_k w[b,k] * V[b, (l+d_k)%T, h*64+e]
// Batch pinned to XCD: b = blockIdx.x % 8 so each batch's 4 MiB V slab stays
// resident in one XCD's 4 MiB L2. V2 stores nontemporal.
__global__ __launch_bounds__(256) void aggregate_kernel(
    const _Float16* __restrict__ V, const float* __restrict__ wgt,
    const int* __restrict__ dly, _Float16* __restrict__ V2) {
  int b = blockIdx.x & 7;
  int g = (blockIdx.x >> 3) * 256 + threadIdx.x;  // 0 .. T*C/8-1
  int c8 = g & 127;
  int tp = g >> 7;                              // output row t'
  int h = tp >> 7, lhi = tp & 127;
  int cp = c8 << 3;
  int e0 = cp & 63, lo = cp >> 6;
  int l = lhi * 16 + lo;
  int ch = h * 64 + e0;
  float acc[8];
  #pragma unroll
  for (int j = 0; j < 8; ++j) acc[j] = 0.0f;
  const long long vbase = (long long)b * T_LEN * C_DIM;
  for (int k = 0; k < TOPK; ++k) {
    float w = wgt[b * TOPK + k];
    int d = dly[b * TOPK + k];
    int ts = (l + d) & (T_LEN - 1);
    half8 vv = *(const half8*)(V + vbase + (long long)ts * C_DIM + ch);
    #pragma unroll
    for (int j = 0; j < 8; ++j) acc[j] += w * (float)vv[j];
  }
  half8 o;
  #pragma unroll
  for (int j = 0; j < 8; ++j) o[j] = (_Float16)acc[j];
  __builtin_nontemporal_store(o, (half8*)(V2 + vbase + (long long)tp * C_DIM + cp));
}

// ---------------------------------------------------------------- launcher
extern "C" void kernel_launch(void* const* d_in, const int* in_sizes, int n_in,
                              void* d_out, int out_size, void* d_ws, size_t ws_size,
                              hipStream_t stream) {
  const float* x  = (const float*)d_in[0];
  const float* Wq = (const float*)d_in[1];
  const float* bq = (const float*)d_in[2];
  const float* Wk = (const float*)d_in[3];
  const float* bk = (const float*)d_in[4];
  const float* Wv = (const float*)d_in[5];
  const float* bv = (const float*)d_in[6];
  const float* Wp = (const float*)d_in[7];
  const float* bp = (const float*)d_in[8];
  (void)bq; (void)bk;  // constant (l-independent) shift of meanv; top-k order and
                       // softmax are shift-invariant (and both are zeros here anyway)

  // Q.K^T == X (Wq Wk^T) X^T  -> drop the K projection entirely.
  // d_out (64 MiB f32 out) doubles as scratch:
  //   [0, 32MiB)   xh fp16 (x converted)  -- live until V-proj done
  //   [32,34) Wqh  [34,36) Wkh  (row-major fp16)   [36,38) Wvt   [38,40) Mt2
  // ws (>= 64MiB + 72KiB, proven):
  //   [0, 32MiB)   XMh fp16 -> later V2 fp16
  //   [32, 64MiB)  V fp16   -> later Wpt
  //   tail: meanv (64KiB), wgt, dly
  const size_t SZ_H = (size_t)B_DIM * T_LEN * C_DIM * 2;   // 32 MiB
  const size_t NEEDED = 2 * SZ_H + 65536 + 8192;
  if (ws_size < NEEDED) return;

  char* ws = (char*)d_ws;
  _Float16* XMh = (_Float16*)ws;
  _Float16* V   = (_Float16*)(ws + SZ_H);
  float* meanv = (float*)(ws + 2 * SZ_H);
  float* wgt   = (float*)(ws + 2 * SZ_H + 65536);
  int*   dly   = (int*)(ws + 2 * SZ_H + 65536 + 4096);
  _Float16* V2  = (_Float16*)ws;             // after Gram (XMh dead)
  _Float16* Wpt = (_Float16*)(ws + SZ_H);    // after agg (V dead), 2 MiB

  char* dob = (char*)d_out;
  _Float16* xh  = (_Float16*)dob;
  _Float16* Wqh = (_Float16*)(dob + 32 * 1048576);
  _Float16* Wkh = (_Float16*)(dob + 34 * 1048576);
  _Float16* Wvt = (_Float16*)(dob + 36 * 1048576);
  _Float16* Mt2 = (_Float16*)(dob + 38 * 1048576);

  const int M = B_DIM * T_LEN;  // 16384
  const long long TC = (long long)T_LEN * C_DIM;

  zero_kernel<<<(B_DIM * T_LEN) / 256, 256, 0, stream>>>(meanv, B_DIM * T_LEN);
  cvt_f16_kernel<<<(M * C_DIM / 8) / 256, 256, 0, stream>>>(x, xh, M * C_DIM / 8);
  cvt_f16_kernel<<<(C_DIM * C_DIM / 8) / 256, 256, 0, stream>>>(Wq, Wqh, C_DIM * C_DIM / 8);
  cvt_f16_kernel<<<(C_DIM * C_DIM / 8) / 256, 256, 0, stream>>>(Wk, Wkh, C_DIM * C_DIM / 8);

  dim3 tgrid(16, 16, 1);
  wt3_kernel<<<tgrid, 256, 0, stream>>>(Wv, Wv, Wv, Wvt, Wvt, Wvt);   // z=0 slice only

  dim3 pgrid(M / 128, C_DIM / 128, 1);        // (128, 8)
  dim3 mgrid(C_DIM / 128, C_DIM / 128, 1);    // (8, 8)
  dim3 ggrid(T_LEN / 128, T_LEN / 128, B_DIM);// (16, 16, 8)

  // Mt2[b,a] = sum_o Wk[b,o] * Wq[a,o]   (both row-major, K-contiguous: NT gemm)
  gemm_f16_kernel<0><<<mgrid, 256, 0, stream>>>(Wkh, Wqh, nullptr, Mt2, nullptr, C_DIM, C_DIM, 0, 0);
  // XM[t,b] = sum_a x[t,a] * Mt2[b,a] = sum_o Q[t,o] Wk[b,o]
  gemm_f16_kernel<0><<<pgrid, 256, 0, stream>>>(xh, Mt2, nullptr, XMh, nullptr, C_DIM, C_DIM, 0, 0);
  // G[t,u] = sum_b XM[t,b] x[u,b] = sum_o Q[t,o] K[u,o]  -> diagonal reduce
  gemm_f16_kernel<2><<<ggrid, 256, 0, stream>>>(XMh, xh, nullptr, nullptr, meanv, T_LEN, C_DIM, TC, TC);

  topk_softmax_kernel<<<B_DIM, 256, 0, stream>>>(meanv, wgt, dly);

  // V = xh @ Wvt + bv  (XMh dead after Gram; stream-ordered)
  gemm_f16_kernel<0><<<pgrid, 256, 0, stream>>>(xh, Wvt, bv, V, nullptr, C_DIM, C_DIM, 0, 0);

  aggregate_kernel<<<(T_LEN * C_DIM / 8 / 256) * B_DIM, 256, 0, stream>>>(V, wgt, dly, V2);

  wt3_kernel<<<tgrid, 256, 0, stream>>>(Wp, Wp, Wp, Wpt, Wpt, Wpt);  // z=0 slice only

  // out = V2 @ Wpt + bp -> d_out f32 (xh + weight slots dead)
  gemm_f16_kernel<1><<<pgrid, 256, 0, stream>>>(V2, Wpt, bp, d_out, nullptr, C_DIM, C_DIM, 0, 0);
}